// Round 13
// baseline (1466.745 us; speedup 1.0000x reference)
//
#include <hip/hip_runtime.h>
#include <cmath>

#define NB 8
#define NPTS 2048
#define NE (NB * NPTS)
#define THREADS 512
#define NBLK 512
#define NPHASE 20
#define NPAIR 2   // packed row-pairs per wave -> 4 rows/wave/half

typedef float v2f __attribute__((ext_vector_type(2)));

#if defined(__has_builtin)
#if __has_builtin(__builtin_amdgcn_exp2f)
#define FAST_EXP2(x) __builtin_amdgcn_exp2f(x)
#else
#define FAST_EXP2(x) exp2f(x)
#endif
#if __has_builtin(__builtin_amdgcn_logf)
#define FAST_LOG2(x) __builtin_amdgcn_logf(x)
#else
#define FAST_LOG2(x) log2f(x)
#endif
#else
#define FAST_EXP2(x) exp2f(x)
#define FAST_LOG2(x) log2f(x)
#endif

// ---- DPP wave64 reductions (VALU pipe only; result valid at lane 63) ----
template<int CTRL>
__device__ __forceinline__ float dpp_f(float v) {
    return __int_as_float(__builtin_amdgcn_update_dpp(
        __float_as_int(v), __float_as_int(v), CTRL, 0xF, 0xF, false));
}
__device__ __forceinline__ float wred_max(float v) {
    v = fmaxf(v, dpp_f<0xB1>(v));
    v = fmaxf(v, dpp_f<0x4E>(v));
    v = fmaxf(v, dpp_f<0x141>(v));
    v = fmaxf(v, dpp_f<0x140>(v));
    v = fmaxf(v, dpp_f<0x142>(v));
    v = fmaxf(v, dpp_f<0x143>(v));
    return v;
}
__device__ __forceinline__ float wred_sum(float v) {
    v += dpp_f<0xB1>(v);
    v += dpp_f<0x4E>(v);
    v += dpp_f<0x141>(v);
    v += dpp_f<0x140>(v);
    v += dpp_f<0x142>(v);
    v += dpp_f<0x143>(v);
    return v;
}

// 2-level monotonic grid barrier (no cooperative launch needed; all NBLK
// blocks are guaranteed co-resident at 2 blocks/CU vs capacity 4).
// Counters monotone across the kernel; zeroed host-side each call.
__device__ __forceinline__ void grid_barrier(unsigned* c1, unsigned* c2,
                                             unsigned* gen, unsigned target)
{
    __syncthreads();                       // drains block's stores (vmcnt)
    if (threadIdx.x == 0) {
        __threadfence();                   // device-scope release of block data
        const int g = blockIdx.x >> 3;     // 64 groups of 8 blocks
        unsigned t1 = __hip_atomic_fetch_add(&c1[g], 1u, __ATOMIC_ACQ_REL,
                                             __HIP_MEMORY_SCOPE_AGENT);
        if ((t1 & 7u) == 7u) {
            unsigned t2 = __hip_atomic_fetch_add(c2, 1u, __ATOMIC_ACQ_REL,
                                                 __HIP_MEMORY_SCOPE_AGENT);
            if ((t2 & 63u) == 63u)
                __hip_atomic_fetch_add(gen, 1u, __ATOMIC_RELEASE,
                                       __HIP_MEMORY_SCOPE_AGENT);
        }
        long cap = 100000000;              // bounded spin: fail, don't hang
        while (__hip_atomic_load(gen, __ATOMIC_ACQUIRE,
                                 __HIP_MEMORY_SCOPE_AGENT) < target && --cap)
            __builtin_amdgcn_s_sleep(2);
    }
    __syncthreads();
}

// Persistent annealed Sinkhorn: all 20 phases in one plain-launched kernel.
// 512 blocks x 512 thr (2 blk/CU, 16 waves/CU; capacity 4 blk/CU -> 2x
// co-residency margin). Block owns 64 rows of one (side,batch): two 32-row
// halves share one hc tile per phase. xy + log2 w staged in LDS once.
// Potentials + LSE stabilizer in registers; opposite side's potentials
// cross through global (ping-pong) with release/acquire at the barrier.
__global__ __launch_bounds__(THREADS, 8) void sinkhorn_persistent(
    const float* __restrict__ x, const float* __restrict__ y,
    const float* __restrict__ a, const float* __restrict__ b,
    float* __restrict__ pot0, float* __restrict__ pot1,
    float* __restrict__ partials, unsigned* __restrict__ bar,
    float* __restrict__ out)
{
    __shared__ float4 xy4[NPTS / 2];   // 16 KB {x2k,y2k,x2k+1,y2k+1}
    __shared__ float2 hc2[NPTS / 2];   // 8 KB log2-domain column constant
    __shared__ float bse[NPTS];        // 8 KB log2(w_col)
    __shared__ float pw[8];

    unsigned* c1 = bar;        // [64]
    unsigned* c2 = bar + 64;
    unsigned* gen = bar + 65;

    const int blk = blockIdx.x;
    const int side = blk >> 8;          // 256 blocks/side
    const int rblk = blk & 255;
    const int batch = rblk >> 5;        // 32 row-tiles (64 rows) per batch
    const int rowTile = rblk & 31;

    const float* rowPts = side ? y : x;
    const float* colPts = side ? x : y;
    const float* wcol   = side ? a : b;
    const float* wrow   = side ? b : a;

    const float LOG2E = 1.4426950408889634f;
    const float LN2 = 0.69314718055994531f;

    // ---- one-time staging ----
    const float4* cp4 = ((const float4*)colPts) + (size_t)batch * (NPTS / 2);
    xy4[threadIdx.x]       = cp4[threadIdx.x];
    xy4[threadIdx.x + 512] = cp4[threadIdx.x + 512];
    {
        const float* wl = wcol + (size_t)batch * NPTS;
        #pragma unroll
        for (int k = 0; k < NPTS / THREADS; k++) {
            int j = threadIdx.x + k * THREADS;
            bse[j] = FAST_LOG2(wl[j]);
        }
    }

    const int lane = threadIdx.x & 63;
    const int wv = threadIdx.x >> 6;

    float fown[8], Lown[8];
    #pragma unroll
    for (int r = 0; r < 8; r++) { fown[r] = 0.0f; Lown[r] = 0.0f; }

    // ---- phase loop ----
    double ecur = 4.0, eprev = 4.0;
    for (int ph = 0; ph < NPHASE; ph++) {
        if (ph >= 2 && ph <= 17)      { eprev = ecur; ecur *= 0.64; }
        else if (ph == 18)            { eprev = ecur; ecur = 0.0025; }
        else                          { eprev = ecur; }
        const int init = (ph == 0);
        const int fin  = (ph == NPHASE - 1);
        const float c_old = (init || fin) ? 0.0f : 0.5f;
        const float c_new = (init || fin) ? 1.0f : 0.5f;
        const float eps = (float)ecur;
        const float mscale = (float)(eprev / ecur);
        const float sc = (float)(1.0 / ecur) * LOG2E;

        const float* potR = (ph & 1) ? pot1 : pot0;
        float* potW       = (ph & 1) ? pot0 : pot1;

        // stage hc: hc_j = log2 w_j + (pot_j - |p_j|^2/2) * sc
        {
            float* hcs = (float*)hc2;
            const float2* xys = (const float2*)xy4;
            const float* pp = potR + (1 - side) * NE + batch * NPTS;
            #pragma unroll
            for (int k = 0; k < NPTS / THREADS; k++) {
                int j = threadIdx.x + k * THREADS;
                float2 p = xys[j];
                float n2 = -0.5f * fmaf(p.x, p.x, p.y * p.y);
                float t = init ? n2 : (pp[j] + n2);
                hcs[j] = fmaf(t, sc, bse[j]);
            }
        }
        __syncthreads();

        float part = 0.0f;
        #pragma unroll
        for (int half = 0; half < 2; half++) {
            const int row0 = rowTile * 64 + half * 32 + wv * (2 * NPAIR);
            const int gidx0 = batch * NPTS + row0;
            const float2* rp2 = (const float2*)(rowPts + (size_t)batch * NPTS * 2) + row0;

            v2f rxp[NPAIR], ryp[NPAIR], nmest[NPAIR], sp[NPAIR];
            float pxl[4], pyl[4];
            #pragma unroll
            for (int p = 0; p < NPAIR; p++) {
                float2 p0 = rp2[2 * p];
                float2 p1 = rp2[2 * p + 1];
                pxl[2 * p] = p0.x; pyl[2 * p] = p0.y;
                pxl[2 * p + 1] = p1.x; pyl[2 * p + 1] = p1.y;
                rxp[p] = (v2f){p0.x * sc, p1.x * sc};
                ryp[p] = (v2f){p0.y * sc, p1.y * sc};
                float m0 = init ? 0.0f : Lown[half * 4 + 2 * p] * mscale;
                float m1 = init ? 0.0f : Lown[half * 4 + 2 * p + 1] * mscale;
                nmest[p] = (v2f){-m0, -m1};
                sp[p] = (v2f){0.0f, 0.0f};
            }

            #pragma unroll 4
            for (int it = 0; it < NPTS / 128; it++) {
                float4 v = xy4[(it << 6) + lane];
                float2 h = hc2[(it << 6) + lane];
                #pragma unroll
                for (int p = 0; p < NPAIR; p++) {
                    v2f h0 = (v2f){h.x, h.x} + nmest[p];
                    v2f h1 = (v2f){h.y, h.y} + nmest[p];
                    v2f t0 = __builtin_elementwise_fma(rxp[p], (v2f){v.x, v.x},
                                __builtin_elementwise_fma(ryp[p], (v2f){v.y, v.y}, h0));
                    v2f t1 = __builtin_elementwise_fma(rxp[p], (v2f){v.z, v.z},
                                __builtin_elementwise_fma(ryp[p], (v2f){v.w, v.w}, h1));
                    sp[p] += (v2f){FAST_EXP2(t0.x), FAST_EXP2(t0.y)};
                    sp[p] += (v2f){FAST_EXP2(t1.x), FAST_EXP2(t1.y)};
                }
            }
            float s[4];
            #pragma unroll
            for (int p = 0; p < NPAIR; p++) {
                s[2 * p]     = wred_sum(sp[p].x);
                s[2 * p + 1] = wred_sum(sp[p].y);
            }

            int bad = 0;
            if (lane == 63) {
                #pragma unroll
                for (int r = 0; r < 4; r++)
                    bad |= !(s[r] > 1e-30f && s[r] < 1e34f);
            }
            float mesc[4];
            #pragma unroll
            for (int p = 0; p < NPAIR; p++) {
                mesc[2 * p] = -nmest[p].x; mesc[2 * p + 1] = -nmest[p].y;
            }

            if (__any(bad)) {
                v2f mm[NPAIR];
                #pragma unroll
                for (int p = 0; p < NPAIR; p++) mm[p] = (v2f){-3.4e38f, -3.4e38f};
                #pragma unroll 4
                for (int it = 0; it < NPTS / 128; it++) {
                    float4 v = xy4[(it << 6) + lane];
                    float2 h = hc2[(it << 6) + lane];
                    #pragma unroll
                    for (int p = 0; p < NPAIR; p++) {
                        v2f h0 = (v2f){h.x, h.x} + nmest[p];
                        v2f h1 = (v2f){h.y, h.y} + nmest[p];
                        v2f t0 = __builtin_elementwise_fma(rxp[p], (v2f){v.x, v.x},
                                    __builtin_elementwise_fma(ryp[p], (v2f){v.y, v.y}, h0));
                        v2f t1 = __builtin_elementwise_fma(rxp[p], (v2f){v.z, v.z},
                                    __builtin_elementwise_fma(ryp[p], (v2f){v.w, v.w}, h1));
                        mm[p] = __builtin_elementwise_max(mm[p],
                                    __builtin_elementwise_max(t0, t1));
                    }
                }
                float mmsc[4];
                #pragma unroll
                for (int p = 0; p < NPAIR; p++) {
                    mmsc[2 * p] = mm[p].x; mmsc[2 * p + 1] = mm[p].y;
                }
                #pragma unroll
                for (int r = 0; r < 4; r++) {
                    mmsc[r] = wred_max(mmsc[r]);
                    mmsc[r] = __shfl(mmsc[r], 63);
                }
                v2f mmb[NPAIR];
                #pragma unroll
                for (int p = 0; p < NPAIR; p++) {
                    mmb[p] = (v2f){mmsc[2 * p], mmsc[2 * p + 1]};
                    sp[p] = (v2f){0.0f, 0.0f};
                }
                #pragma unroll 4
                for (int it = 0; it < NPTS / 128; it++) {
                    float4 v = xy4[(it << 6) + lane];
                    float2 h = hc2[(it << 6) + lane];
                    #pragma unroll
                    for (int p = 0; p < NPAIR; p++) {
                        v2f h0 = (v2f){h.x, h.x} + nmest[p] - mmb[p];
                        v2f h1 = (v2f){h.y, h.y} + nmest[p] - mmb[p];
                        v2f t0 = __builtin_elementwise_fma(rxp[p], (v2f){v.x, v.x},
                                    __builtin_elementwise_fma(ryp[p], (v2f){v.y, v.y}, h0));
                        v2f t1 = __builtin_elementwise_fma(rxp[p], (v2f){v.z, v.z},
                                    __builtin_elementwise_fma(ryp[p], (v2f){v.w, v.w}, h1));
                        sp[p] += (v2f){FAST_EXP2(t0.x), FAST_EXP2(t0.y)};
                        sp[p] += (v2f){FAST_EXP2(t1.x), FAST_EXP2(t1.y)};
                    }
                }
                #pragma unroll
                for (int p = 0; p < NPAIR; p++) {
                    s[2 * p]     = wred_sum(sp[p].x);
                    s[2 * p + 1] = wred_sum(sp[p].y);
                    mesc[2 * p] += mmb[p].x;
                    mesc[2 * p + 1] += mmb[p].y;
                }
            }

            // epilogue (uniform via lane-63 broadcast)
            #pragma unroll
            for (int r = 0; r < 4; r++) {
                float sb = __shfl(s[r], 63);
                float L = mesc[r] + FAST_LOG2(sb);
                Lown[half * 4 + r] = L;
                float hr = -0.5f * sc * fmaf(pxl[r], pxl[r], pyl[r] * pyl[r]);
                float sm = -eps * LN2 * (hr + L);
                fown[half * 4 + r] = c_old * fown[half * 4 + r] + c_new * sm;
            }
            if (lane == 63) {
                #pragma unroll
                for (int r = 0; r < 4; r++)
                    potW[side * NE + gidx0 + r] = fown[half * 4 + r];
                if (fin) {
                    #pragma unroll
                    for (int r = 0; r < 4; r++)
                        part += wrow[gidx0 + r] * fown[half * 4 + r];
                }
            }
        }

        if (fin) {
            if (lane == 63) pw[wv] = part;
            __syncthreads();
            if (threadIdx.x == 0) {
                float t = 0.0f;
                #pragma unroll
                for (int i = 0; i < 8; i++) t += pw[i];
                partials[blk] = t;
            }
        }
        grid_barrier(c1, c2, gen, (unsigned)(ph + 1));
    }

    // final reduction of 512 partials by block 0
    if (blk == 0) {
        float v = partials[threadIdx.x];
        v = wred_sum(v);
        if (lane == 63) pw[wv] = v;
        __syncthreads();
        if (threadIdx.x == 0) {
            float t = 0.0f;
            #pragma unroll
            for (int i = 0; i < 8; i++) t += pw[i];
            out[0] = t * (1.0f / NB);
        }
    }
}

extern "C" void kernel_launch(void* const* d_in, const int* in_sizes, int n_in,
                              void* d_out, int out_size, void* d_ws, size_t ws_size,
                              hipStream_t stream)
{
    const float* a = (const float*)d_in[0];
    const float* x = (const float*)d_in[1];
    const float* b = (const float*)d_in[2];
    const float* y = (const float*)d_in[3];
    float* out = (float*)d_out;

    float* ws = (float*)d_ws;
    float* pot0 = ws;                   // [2][NB][NPTS]
    float* pot1 = ws + 2 * NE;          // [2][NB][NPTS]
    float* partials = ws + 4 * NE;      // 512 floats
    unsigned* bar = (unsigned*)(ws + 4 * NE + 1024);  // c1[64], c2, gen

    (void)hipMemsetAsync(bar, 0, 66 * sizeof(unsigned), stream);
    sinkhorn_persistent<<<NBLK, THREADS, 0, stream>>>(
        x, y, a, b, pot0, pot1, partials, bar, out);
}